// Round 7
// baseline (293.473 us; speedup 1.0000x reference)
//
#include <hip/hip_runtime.h>
#include <hip/hip_cooperative_groups.h>
#include <math.h>

namespace cg = cooperative_groups;

#define LEN 4096
#define LOG2LEN 12
#define DH 64
#define NBH 32      // B*H
#define KTOP 8

#define ZT_ELEMS ((size_t)NBH * DH * LEN)   // float2 count (67 MB)
#define TW_N (LEN / 2)                      // 2048 float2 twiddles
#define SPEC_F2 (NBH * LEN)                 // 131072 float2 (1 MB)

// padded exchange layout: array a (=top digit), slot c in [0,256): a*272 + c
// (272 % 32 == 16 -> every exchange pattern is <=2-way conflicted = free)
#define XSTR 272

// shared-memory block used by all phases (36.9 KB -> 4 blocks/CU)
struct SmemFFT {
  float lre[16 * XSTR];
  float lim[16 * XSTR];
  float rv[256];
  int ri[256];
  float selv[KTOP];
  int seli[KTOP];
};

// base-16 digit reversal of a 12-bit index (3 hex digits)
__device__ __forceinline__ int rev16_12(int x) {
  return ((x & 15) << 8) | (x & 240) | (x >> 8);
}

// twiddle fetch from global half-table tw[j] = (cos(2pi j/L), sin(2pi j/L));
// SIM = -1 forward, +1 inverse. e in [0, 4096).
template <int SIM>
__device__ __forceinline__ void twget(const float2* __restrict__ tw, int e,
                                      float& wr, float& wi) {
  const float2 t = tw[e & (TW_N - 1)];
  const float sgn = (e & TW_N) ? -1.0f : 1.0f;
  wr = sgn * t.x;
  wi = sgn * (float)SIM * t.y;
}

// ---------------- in-register complex helpers / 16-point DFT ----------------
struct cf { float r, i; };
__device__ __forceinline__ cf cadd(const cf a, const cf b) { return {a.r + b.r, a.i + b.i}; }
__device__ __forceinline__ cf csub(const cf a, const cf b) { return {a.r - b.r, a.i - b.i}; }
__device__ __forceinline__ cf cmul(const cf a, const float wr, const float wi) {
  return {a.r * wr - a.i * wi, a.r * wi + a.i * wr};
}
// multiply by W^(N/4): forward (-i), inverse (+i)
template <int S>
__device__ __forceinline__ cf cmuli(const cf a) {
  return (S < 0) ? cf{a.i, -a.r} : cf{-a.i, a.r};
}
// multiply by (c, S*s)
template <int S>
__device__ __forceinline__ cf twc(const cf a, const float c, const float s) {
  return cmul(a, c, (S < 0) ? -s : s);
}
template <int S>
__device__ __forceinline__ void r4(cf& a, cf& b, cf& c, cf& d) {
  const cf t0 = cadd(a, c), t1 = csub(a, c), t2 = cadd(b, d), t3 = csub(b, d);
  const cf j3 = cmuli<S>(t3);
  a = cadd(t0, t2); c = csub(t0, t2);
  b = cadd(t1, j3); d = csub(t1, j3);
}
// 16-point DFT, natural order in and out, compile-time twiddles.
template <int S>
__device__ __forceinline__ void dft16(cf* x) {
  r4<S>(x[0], x[4], x[8], x[12]);
  r4<S>(x[1], x[5], x[9], x[13]);
  r4<S>(x[2], x[6], x[10], x[14]);
  r4<S>(x[3], x[7], x[11], x[15]);
  const float C1 = 0.92387953251128675613f;  // cos(pi/8)
  const float S1 = 0.38268343236508977173f;  // sin(pi/8)
  const float R2 = 0.70710678118654752440f;
  // slot n2+4k1 *= W16^{n2*k1}
  x[5] = twc<S>(x[5], C1, S1);
  x[6] = twc<S>(x[6], R2, R2);
  x[7] = twc<S>(x[7], S1, C1);
  x[9] = twc<S>(x[9], R2, R2);
  x[10] = cmuli<S>(x[10]);
  x[11] = twc<S>(x[11], -R2, R2);
  x[13] = twc<S>(x[13], S1, C1);
  x[14] = twc<S>(x[14], -R2, R2);
  x[15] = twc<S>(x[15], -C1, -S1);
  r4<S>(x[0], x[1], x[2], x[3]);
  r4<S>(x[4], x[5], x[6], x[7]);
  r4<S>(x[8], x[9], x[10], x[11]);
  r4<S>(x[12], x[13], x[14], x[15]);
  // slot(4k1+k2) holds X[4k2+k1] -> transpose to natural order
  cf t;
  t = x[1]; x[1] = x[4]; x[4] = t;
  t = x[2]; x[2] = x[8]; x[8] = t;
  t = x[3]; x[3] = x[12]; x[12] = t;
  t = x[6]; x[6] = x[9]; x[9] = t;
  t = x[7]; x[7] = x[13]; x[13] = t;
  t = x[11]; x[11] = x[14]; x[14] = t;
}

// ---------------------------------------------------------------------------
// Phase T task: transpose one 64t x 64d tile of q,k into packed complex
// zT[(bh*64+d)*LEN + t], z = q + i*k. Coalesced both sides via padded LDS.
// task = bh*64 + tchunk. Uses sm.lre/sm.lim as the tile buffers (4160<=4352).
// ---------------------------------------------------------------------------
__device__ __forceinline__ void transpose_task(int task, const float* __restrict__ q,
                                               const float* __restrict__ k,
                                               float2* __restrict__ zT, SmemFFT& sm) {
  float (*tq)[65] = reinterpret_cast<float(*)[65]>(sm.lre);
  float (*tk)[65] = reinterpret_cast<float(*)[65]>(sm.lim);
  const int bh = task >> 6;
  const int t0 = (task & 63) * 64;
  const int tid = threadIdx.x;
  const int tl = tid >> 2;
  const int c = tid & 3;
  const float* qb = q + ((size_t)bh * LEN + t0) * DH;
  const float* kb = k + ((size_t)bh * LEN + t0) * DH;
#pragma unroll
  for (int r = 0; r < 4; ++r) {
    const int d0 = (c + r * 4) * 4;
    const float4 vq = *reinterpret_cast<const float4*>(qb + (size_t)tl * DH + d0);
    const float4 vk = *reinterpret_cast<const float4*>(kb + (size_t)tl * DH + d0);
    tq[tl][d0] = vq.x; tq[tl][d0 + 1] = vq.y; tq[tl][d0 + 2] = vq.z; tq[tl][d0 + 3] = vq.w;
    tk[tl][d0] = vk.x; tk[tl][d0 + 1] = vk.y; tk[tl][d0 + 2] = vk.z; tk[tl][d0 + 3] = vk.w;
  }
  __syncthreads();
  const int d = tid >> 2;
  const int s = tid & 3;
  float2* ob = zT + ((size_t)(bh * DH + d)) * LEN + t0;
#pragma unroll
  for (int r = 0; r < 8; ++r) {
    const int t = (s + r * 4) * 2;
    const float4 o = make_float4(tq[t][d], tk[t][d], tq[t + 1][d], tk[t + 1][d]);
    *reinterpret_cast<float4*>(&ob[t]) = o;
  }
}

// ---------------------------------------------------------------------------
// Phase F task: one (bh,d) slab. Forward FFT of z = q_d + i*k_d as 16x16x16
// (three in-register 16-pt DFTs + 2 LDS exchanges); output position p holds
// Z[rev16(p)]. Cross-spectrum P[f] = Q conj(K) = Im(A*B)/2 + i(|A|^2-|B|^2)/4
// (A=Z[f], B=Z[-f]) written over the slab it consumed (read-all-before-write).
// ---------------------------------------------------------------------------
template <bool TR>
__device__ __forceinline__ void fwd_task(int slabid, const float* __restrict__ q,
                                         const float* __restrict__ k,
                                         const float2* __restrict__ zin,
                                         const float2* __restrict__ tw,
                                         float2* __restrict__ pout, SmemFFT& sm) {
  float* lre = sm.lre;
  float* lim = sm.lim;
  const int tid = threadIdx.x;
  const int hi = tid >> 4, lo = tid & 15;
  const size_t slab = (size_t)slabid * LEN;

  cf x[16];
  if (TR) {
    const float2* zb = zin + slab;
#pragma unroll
    for (int n1 = 0; n1 < 16; ++n1) {
      const float2 z = zb[tid + 256 * n1];
      x[n1].r = z.x; x[n1].i = z.y;
    }
  } else {
    const int bh = slabid >> 6;
    const int d = slabid & 63;
    const float* qb = q + (size_t)bh * LEN * DH + d;
    const float* kb = k + (size_t)bh * LEN * DH + d;
#pragma unroll
    for (int n1 = 0; n1 < 16; ++n1) {
      x[n1].r = qb[(size_t)(tid + 256 * n1) * DH];
      x[n1].i = kb[(size_t)(tid + 256 * n1) * DH];
    }
  }
  // stage 1: DFT over n1 (stride 256), twiddle W4096^{n2*k1}, n2 = tid
  dft16<-1>(x);
#pragma unroll
  for (int k1 = 1; k1 < 16; ++k1) {
    float wr, wi;
    twget<-1>(tw, tid * k1, wr, wi);
    x[k1] = cmul(x[k1], wr, wi);
  }
#pragma unroll
  for (int k1 = 0; k1 < 16; ++k1) {
    lre[k1 * XSTR + tid] = x[k1].r;
    lim[k1 * XSTR + tid] = x[k1].i;
  }
  __syncthreads();
  // stage 2 inputs: fixed (k1=hi, m2=lo), over m1
#pragma unroll
  for (int m1 = 0; m1 < 16; ++m1) {
    const int a = hi * XSTR + 16 * m1 + lo;
    x[m1].r = lre[a]; x[m1].i = lim[a];
  }
  dft16<-1>(x);
#pragma unroll
  for (int j1 = 1; j1 < 16; ++j1) {  // twiddle W256^{m2*j1} = W4096^{16*lo*j1}
    float wr, wi;
    twget<-1>(tw, 16 * lo * j1, wr, wi);
    x[j1] = cmul(x[j1], wr, wi);
  }
  __syncthreads();  // all stage-2 reads done
#pragma unroll
  for (int j1 = 0; j1 < 16; ++j1) {
    lre[hi * XSTR + 16 * j1 + lo] = x[j1].r;
    lim[hi * XSTR + 16 * j1 + lo] = x[j1].i;
  }
  __syncthreads();
  // stage 3 inputs: fixed (k1=hi, j1=lo), over m2 (contiguous 16)
#pragma unroll
  for (int m2 = 0; m2 < 16; ++m2) {
    const int a = hi * XSTR + 16 * lo + m2;
    x[m2].r = lre[a]; x[m2].i = lim[a];
  }
  dft16<-1>(x);
  __syncthreads();  // all stage-3 reads done
#pragma unroll
  for (int j2 = 0; j2 < 16; ++j2) {  // p = 256*hi + 16*lo + j2
    lre[hi * XSTR + 16 * lo + j2] = x[j2].r;
    lim[hi * XSTR + 16 * lo + j2] = x[j2].i;
  }
  __syncthreads();
  // cross-spectrum pairing (position p holds Z[rev16(p)]); write straight out
  float2* op = pout + slab;
#pragma unroll
  for (int i = 0; i < 16; ++i) {
    const int p = tid + 256 * i;
    const int f = rev16_12(p);
    const int f2 = (LEN - f) & (LEN - 1);
    const int p2 = rev16_12(f2);
    const int a1 = i * XSTR + tid;
    const int a2 = (p2 >> 8) * XSTR + (p2 & 255);
    const float ar = lre[a1], ai = lim[a1];
    const float br = lre[a2], bi = lim[a2];
    op[p] = make_float2(0.5f * (ar * bi + ai * br),
                        0.25f * ((ar * ar + ai * ai) - (br * br + bi * bi)));
  }
}

// ---------------------------------------------------------------------------
// Phase R task: sum 64 partial spectra. task = bh*32 + chunk; 256 floats each.
// ---------------------------------------------------------------------------
__device__ __forceinline__ void reduce_task(int task, const float2* __restrict__ part,
                                            float2* __restrict__ spec) {
  const int bh = task >> 5;
  const int fi = ((task & 31) << 8) | (int)threadIdx.x;  // float index 0..8191
  const float* base = (const float*)(part + (((size_t)bh * DH) << LOG2LEN));
  float acc = 0.f;
#pragma unroll 8
  for (int g = 0; g < DH; ++g) acc += base[((size_t)g << (LOG2LEN + 1)) + fi];
  ((float*)spec)[(((size_t)bh) << (LOG2LEN + 1)) + fi] = acc;
}

// ---------------------------------------------------------------------------
// Phase I task: per (b,h): inverse FFT 16x16x16 (digit-reversed in -> natural
// out) fused with top-8 + softmax. Writes attn + delays only.
// ---------------------------------------------------------------------------
__device__ __forceinline__ void inv_task(int bh, const float2* __restrict__ spec,
                                         const float2* __restrict__ tw,
                                         float* __restrict__ attn,
                                         int* __restrict__ delays, SmemFFT& sm) {
  float* lre = sm.lre;
  float* lim = sm.lim;
  const int tid = threadIdx.x;
  const int hi = tid >> 4, lo = tid & 15;
  const float2* sp = spec + ((size_t)bh << LOG2LEN);

  // input: position p = 16*tid + f2 holds P[rev16(p)]; thread = (f0=hi, f1=lo)
  cf x[16];
#pragma unroll
  for (int f2 = 0; f2 < 16; ++f2) {
    const float2 z = sp[16 * tid + f2];
    x[f2].r = z.x; x[f2].i = z.y;
  }
  // stage A: DFT over f2 -> A1[t0]; twiddle W4096^{16*f1*t0}
  dft16<1>(x);
#pragma unroll
  for (int t0 = 1; t0 < 16; ++t0) {
    float wr, wi;
    twget<1>(tw, 16 * lo * t0, wr, wi);
    x[t0] = cmul(x[t0], wr, wi);
  }
#pragma unroll
  for (int t0 = 0; t0 < 16; ++t0) {
    lre[hi * XSTR + 16 * t0 + lo] = x[t0].r;
    lim[hi * XSTR + 16 * t0 + lo] = x[t0].i;
  }
  __syncthreads();
  // stage B: thread (f0=hi, t0=lo), over f1 (contiguous)
#pragma unroll
  for (int f1 = 0; f1 < 16; ++f1) {
    const int a = hi * XSTR + 16 * lo + f1;
    x[f1].r = lre[a]; x[f1].i = lim[a];
  }
  dft16<1>(x);
#pragma unroll
  for (int t1 = 0; t1 < 16; ++t1) {  // twiddle W4096^{f0*(16*t1+t0)}
    float wr, wi;
    twget<1>(tw, hi * (16 * t1 + lo), wr, wi);
    x[t1] = cmul(x[t1], wr, wi);
  }
  __syncthreads();  // stage-B reads done
#pragma unroll
  for (int t1 = 0; t1 < 16; ++t1) {
    lre[hi * XSTR + 16 * t1 + lo] = x[t1].r;
    lim[hi * XSTR + 16 * t1 + lo] = x[t1].i;
  }
  __syncthreads();
  // stage C: thread (t1=hi, t0=lo), over f0 (stride XSTR)
#pragma unroll
  for (int f0 = 0; f0 < 16; ++f0) {
    const int a = f0 * XSTR + 16 * hi + lo;
    x[f0].r = lre[a]; x[f0].i = lim[a];
  }
  dft16<1>(x);
  __syncthreads();  // stage-C reads done; reuse lre as vals[4096]
  const float scale = 1.0f / ((float)LEN * (float)DH);
#pragma unroll
  for (int t2 = 0; t2 < 16; ++t2) lre[256 * t2 + tid] = x[t2].r * scale;  // t = 256*t2 + tid
  __syncthreads();

  // top-8 + softmax on vals = lre[0..4095]
  for (int kk = 0; kk < KTOP; ++kk) {
    float mv = -3.0e38f;
    int mi = 0;
    for (int t = tid; t < LEN; t += 256) {
      const float xv = lre[t];
      if (xv > mv) { mv = xv; mi = t; }
    }
    sm.rv[tid] = mv; sm.ri[tid] = mi;
    __syncthreads();
    for (int s = 128; s > 0; s >>= 1) {
      if (tid < s) {
        if (sm.rv[tid + s] > sm.rv[tid]) { sm.rv[tid] = sm.rv[tid + s]; sm.ri[tid] = sm.ri[tid + s]; }
      }
      __syncthreads();
    }
    if (tid == 0) {
      sm.selv[kk] = sm.rv[0];
      sm.seli[kk] = sm.ri[0];
      lre[sm.ri[0]] = -3.0e38f;
    }
    __syncthreads();
  }
  if (tid == 0) {
    const float mx = sm.selv[0];
    float ex[KTOP];
    float sum = 0.f;
    for (int j = 0; j < KTOP; ++j) { ex[j] = expf(sm.selv[j] - mx); sum += ex[j]; }
    const float inv = 1.0f / sum;
    for (int j = 0; j < KTOP; ++j) {
      attn[bh * KTOP + j] = ex[j] * inv;
      delays[bh * KTOP + j] = sm.seli[j];
    }
  }
}

// ---------------------------------------------------------------------------
// Phase G task: out[bh,t,d] = sum_j attn_j * v[bh,(t-delay_j) mod L, d].
// ---------------------------------------------------------------------------
__device__ __forceinline__ void gather_task(int bx, const float* __restrict__ v,
                                            const float* __restrict__ attn,
                                            const int* __restrict__ delays,
                                            float* __restrict__ out) {
  const int xcd = bx & 7;
  const int i = bx >> 3;
  const int bh = (xcd << 2) | (i & 3);
  const int chunk = i >> 2;
  const int tid = threadIdx.x;
  float aw[KTOP];
  int dl[KTOP];
#pragma unroll
  for (int j = 0; j < KTOP; ++j) {
    aw[j] = attn[bh * KTOP + j];
    dl[j] = delays[bh * KTOP + j];
  }
  const int e = chunk * 1024 + tid * 4;
  const int t = e >> 6;
  const int d = e & 63;
  const float* vb = v + (size_t)bh * LEN * DH;
  float4 acc = make_float4(0.f, 0.f, 0.f, 0.f);
#pragma unroll
  for (int j = 0; j < KTOP; ++j) {
    int src = t - dl[j];
    if (src < 0) src += LEN;
    const float4 vv = *reinterpret_cast<const float4*>(vb + (size_t)src * DH + d);
    acc.x += aw[j] * vv.x;
    acc.y += aw[j] * vv.y;
    acc.z += aw[j] * vv.z;
    acc.w += aw[j] * vv.w;
  }
  *reinterpret_cast<float4*>(out + (size_t)bh * LEN * DH + e) = acc;
}

// ---------------------------------------------------------------------------
// Fused cooperative kernel: T -> F -> R -> I -> G with grid syncs, one launch.
// ---------------------------------------------------------------------------
__global__ __launch_bounds__(256) void ac_fused(const float* __restrict__ q,
                                                const float* __restrict__ k,
                                                const float* __restrict__ v,
                                                float2* __restrict__ tw,
                                                float2* __restrict__ zT,
                                                float2* __restrict__ spec,
                                                float* __restrict__ attn,
                                                int* __restrict__ delays,
                                                float* __restrict__ out) {
  __shared__ SmemFFT sm;
  const int blk = (int)blockIdx.x;
  const int G = (int)gridDim.x;

  // twiddle table (needed from phase F on)
  for (int j = blk * 256 + (int)threadIdx.x; j < TW_N; j += G * 256) {
    float s, c;
    sincosf(6.2831853071795864769f * (float)j / (float)LEN, &s, &c);
    tw[j] = make_float2(c, s);
  }
  // phase T
  for (int task = blk; task < NBH * 64; task += G) {
    __syncthreads();
    transpose_task(task, q, k, zT, sm);
  }
  cg::this_grid().sync();
  // phase F (writes partials in-place over zT)
  for (int task = blk; task < NBH * DH; task += G) {
    __syncthreads();
    fwd_task<true>(task, q, k, zT, tw, zT, sm);
  }
  cg::this_grid().sync();
  // phase R
  for (int task = blk; task < NBH * 32; task += G) reduce_task(task, zT, spec);
  cg::this_grid().sync();
  // phase I
  for (int task = blk; task < NBH; task += G) {
    __syncthreads();
    inv_task(task, spec, tw, attn, delays, sm);
  }
  cg::this_grid().sync();
  // phase G
  for (int task = blk; task < NBH * 256; task += G) gather_task(task, v, attn, delays, out);
}

// ---------------------------------------------------------------------------
// Fallback standalone kernels (round-5 structure; used if coop launch fails)
// ---------------------------------------------------------------------------
__global__ void k_twinit(float2* __restrict__ tw) {
  const int j = blockIdx.x * 256 + threadIdx.x;
  if (j < TW_N) {
    float s, c;
    sincosf(6.2831853071795864769f * (float)j / (float)LEN, &s, &c);
    tw[j] = make_float2(c, s);
  }
}
__global__ __launch_bounds__(256, 4) void k_transpose(const float* __restrict__ q,
                                                      const float* __restrict__ k,
                                                      float2* __restrict__ zT,
                                                      float2* __restrict__ tw) {
  __shared__ SmemFFT sm;
  if (blockIdx.x < 8) {
    const int j = blockIdx.x * 256 + threadIdx.x;
    float s, c;
    sincosf(6.2831853071795864769f * (float)j / (float)LEN, &s, &c);
    tw[j] = make_float2(c, s);
  }
  transpose_task(blockIdx.x, q, k, zT, sm);
}
__global__ __launch_bounds__(256, 4) void k_fwd_tr(const float* __restrict__ q,
                                                   const float* __restrict__ k,
                                                   const float2* __restrict__ zin,
                                                   const float2* __restrict__ tw,
                                                   float2* __restrict__ pout) {
  __shared__ SmemFFT sm;
  fwd_task<true>(blockIdx.x, q, k, zin, tw, pout, sm);
}
__global__ __launch_bounds__(256, 4) void k_fwd_notr(const float* __restrict__ q,
                                                     const float* __restrict__ k,
                                                     const float2* __restrict__ zin,
                                                     const float2* __restrict__ tw,
                                                     float2* __restrict__ pout) {
  __shared__ SmemFFT sm;
  fwd_task<false>(blockIdx.x, q, k, zin, tw, pout, sm);
}
__global__ __launch_bounds__(256) void k_reduce(const float2* __restrict__ part,
                                                float2* __restrict__ spec) {
  reduce_task(blockIdx.x, part, spec);
}
__global__ __launch_bounds__(256, 4) void k_inv(const float2* __restrict__ spec,
                                                const float2* __restrict__ tw,
                                                float* __restrict__ attn,
                                                int* __restrict__ delays) {
  __shared__ SmemFFT sm;
  inv_task(blockIdx.x, spec, tw, attn, delays, sm);
}
__global__ __launch_bounds__(256) void k_gather(const float* __restrict__ v,
                                                const float* __restrict__ attn,
                                                const int* __restrict__ delays,
                                                float* __restrict__ out) {
  gather_task(blockIdx.x, v, attn, delays, out);
}

extern "C" void kernel_launch(void* const* d_in, const int* in_sizes, int n_in,
                              void* d_out, int out_size, void* d_ws, size_t ws_size,
                              hipStream_t stream) {
  const float* q = (const float*)d_in[0];
  const float* k = (const float*)d_in[1];
  const float* v = (const float*)d_in[2];
  float* out = (float*)d_out;

  // ws layout: tw | zT (reused in-place for partials) | spec | attn | delays
  const size_t need = (size_t)TW_N * 8 + ZT_ELEMS * 8 + (size_t)SPEC_F2 * 8 +
                      (size_t)NBH * KTOP * 8;
  const bool tr = (ws_size >= need);

  float2* tw = (float2*)d_ws;
  float2* zT = tw + TW_N;
  float2* spec = zT + ZT_ELEMS;
  float* attn = (float*)(spec + SPEC_F2);
  int* delays = (int*)(attn + NBH * KTOP);

  bool done = false;
  if (tr) {
    int dev = 0;
    (void)hipGetDevice(&dev);
    int numCU = 0;
    (void)hipDeviceGetAttribute(&numCU, hipDeviceAttributeMultiprocessorCount, dev);
    int maxB = 0;
    (void)hipOccupancyMaxActiveBlocksPerMultiprocessor(&maxB, ac_fused, 256, 0);
    long grid = (long)numCU * (long)maxB;
    if (grid > 2048) grid = 2048;
    if (grid >= 64) {
      void* args[] = {(void*)&q, (void*)&k, (void*)&v, (void*)&tw, (void*)&zT,
                      (void*)&spec, (void*)&attn, (void*)&delays, (void*)&out};
      if (hipLaunchCooperativeKernel(ac_fused, dim3((unsigned)grid), dim3(256), args,
                                     0, stream) == hipSuccess)
        done = true;
    }
  }
  if (!done) {
    if (tr) {
      k_transpose<<<dim3(NBH * 64), dim3(256), 0, stream>>>(q, k, zT, tw);
      k_fwd_tr<<<dim3(NBH * DH), dim3(256), 0, stream>>>(q, k, zT, tw, zT);
    } else {
      k_twinit<<<dim3(8), dim3(256), 0, stream>>>(tw);
      k_fwd_notr<<<dim3(NBH * DH), dim3(256), 0, stream>>>(q, k, zT, tw, zT);
    }
    k_reduce<<<dim3(NBH * 32), dim3(256), 0, stream>>>(zT, spec);
    k_inv<<<dim3(NBH), dim3(256), 0, stream>>>(spec, tw, attn, delays);
    k_gather<<<dim3(NBH * 256 * 8), dim3(256), 0, stream>>>(v, attn, delays, out);
  }
}

// Round 8
// 97.503 us; speedup vs baseline: 3.0099x; 3.0099x over previous
//
#include <hip/hip_runtime.h>
#include <math.h>

#define LEN 4096
#define LOG2LEN 12
#define DH 64
#define NBH 32      // B*H
#define KTOP 8
#define DPB 4       // d's per fwd block (LDS-accumulated)
#define NGRP (DH / DPB)                     // 16 partial slabs per bh

#define ZT_ELEMS ((size_t)NBH * DH * LEN)   // float2 count (67 MB)
#define TW_N (LEN / 2)                      // 2048 float2 twiddles
#define SPEC_F2 (NBH * LEN)                 // 131072 float2 (1 MB)
#define PART_F2 ((size_t)NBH * NGRP * LEN)  // 2M float2 (16.8 MB)

// padded exchange layout: array a (=top digit), slot c in [0,256): a*272 + c
// (272 % 32 == 16 -> every exchange pattern is <=2-way conflicted = free)
#define XSTR 272

// base-16 digit reversal of a 12-bit index (3 hex digits)
__device__ __forceinline__ int rev16_12(int x) {
  return ((x & 15) << 8) | (x & 240) | (x >> 8);
}

// twiddle fetch from global half-table tw[j] = (cos(2pi j/L), sin(2pi j/L));
// SIM = -1 forward, +1 inverse. e in [0, 4096).
template <int SIM>
__device__ __forceinline__ void twget(const float2* __restrict__ tw, int e,
                                      float& wr, float& wi) {
  const float2 t = tw[e & (TW_N - 1)];
  const float sgn = (e & TW_N) ? -1.0f : 1.0f;
  wr = sgn * t.x;
  wi = sgn * (float)SIM * t.y;
}

// ---------------- in-register complex helpers / 16-point DFT ----------------
struct cf { float r, i; };
__device__ __forceinline__ cf cadd(const cf a, const cf b) { return {a.r + b.r, a.i + b.i}; }
__device__ __forceinline__ cf csub(const cf a, const cf b) { return {a.r - b.r, a.i - b.i}; }
__device__ __forceinline__ cf cmul(const cf a, const float wr, const float wi) {
  return {a.r * wr - a.i * wi, a.r * wi + a.i * wr};
}
// multiply by W^(N/4): forward (-i), inverse (+i)
template <int S>
__device__ __forceinline__ cf cmuli(const cf a) {
  return (S < 0) ? cf{a.i, -a.r} : cf{-a.i, a.r};
}
// multiply by (c, S*s)
template <int S>
__device__ __forceinline__ cf twc(const cf a, const float c, const float s) {
  return cmul(a, c, (S < 0) ? -s : s);
}
template <int S>
__device__ __forceinline__ void r4(cf& a, cf& b, cf& c, cf& d) {
  const cf t0 = cadd(a, c), t1 = csub(a, c), t2 = cadd(b, d), t3 = csub(b, d);
  const cf j3 = cmuli<S>(t3);
  a = cadd(t0, t2); c = csub(t0, t2);
  b = cadd(t1, j3); d = csub(t1, j3);
}
// 16-point DFT, natural order in and out, compile-time twiddles.
template <int S>
__device__ __forceinline__ void dft16(cf* x) {
  r4<S>(x[0], x[4], x[8], x[12]);
  r4<S>(x[1], x[5], x[9], x[13]);
  r4<S>(x[2], x[6], x[10], x[14]);
  r4<S>(x[3], x[7], x[11], x[15]);
  const float C1 = 0.92387953251128675613f;  // cos(pi/8)
  const float S1 = 0.38268343236508977173f;  // sin(pi/8)
  const float R2 = 0.70710678118654752440f;
  // slot n2+4k1 *= W16^{n2*k1}
  x[5] = twc<S>(x[5], C1, S1);
  x[6] = twc<S>(x[6], R2, R2);
  x[7] = twc<S>(x[7], S1, C1);
  x[9] = twc<S>(x[9], R2, R2);
  x[10] = cmuli<S>(x[10]);
  x[11] = twc<S>(x[11], -R2, R2);
  x[13] = twc<S>(x[13], S1, C1);
  x[14] = twc<S>(x[14], -R2, R2);
  x[15] = twc<S>(x[15], -C1, -S1);
  r4<S>(x[0], x[1], x[2], x[3]);
  r4<S>(x[4], x[5], x[6], x[7]);
  r4<S>(x[8], x[9], x[10], x[11]);
  r4<S>(x[12], x[13], x[14], x[15]);
  // slot(4k1+k2) holds X[4k2+k1] -> transpose to natural order
  cf t;
  t = x[1]; x[1] = x[4]; x[4] = t;
  t = x[2]; x[2] = x[8]; x[8] = t;
  t = x[3]; x[3] = x[12]; x[12] = t;
  t = x[6]; x[6] = x[9]; x[9] = t;
  t = x[7]; x[7] = x[13]; x[13] = t;
  t = x[11]; x[11] = x[14]; x[14] = t;
}

// ---------------------------------------------------------------------------
// twiddle table init (fallback path only; TR path fuses into transpose)
// ---------------------------------------------------------------------------
__global__ void ac_twinit(float2* __restrict__ tw) {
  const int j = blockIdx.x * 256 + threadIdx.x;
  if (j < TW_N) {
    float s, c;
    sincosf(6.2831853071795864769f * (float)j / (float)LEN, &s, &c);
    tw[j] = make_float2(c, s);
  }
}

// ---------------------------------------------------------------------------
// Pass T: transpose q,k (bh,t,d) -> packed complex zT[(bh*64+d)*LEN + t],
// z = q + i*k. Coalesced both sides via padded LDS tiles. First 8 blocks also
// populate the twiddle table.
// ---------------------------------------------------------------------------
__global__ __launch_bounds__(256, 4) void ac_transpose(const float* __restrict__ q,
                                                       const float* __restrict__ k,
                                                       float2* __restrict__ zT,
                                                       float2* __restrict__ tw) {
  if (blockIdx.x < 8) {
    const int j = blockIdx.x * 256 + threadIdx.x;
    float s, c;
    sincosf(6.2831853071795864769f * (float)j / (float)LEN, &s, &c);
    tw[j] = make_float2(c, s);
  }
  __shared__ float tq[64][65], tk[64][65];
  const int bh = blockIdx.x >> 6;
  const int t0 = (blockIdx.x & 63) * 64;
  const int tid = threadIdx.x;
  const int tl = tid >> 2;
  const int c = tid & 3;
  const float* qb = q + ((size_t)bh * LEN + t0) * DH;
  const float* kb = k + ((size_t)bh * LEN + t0) * DH;
#pragma unroll
  for (int r = 0; r < 4; ++r) {
    const int d0 = (c + r * 4) * 4;
    const float4 vq = *reinterpret_cast<const float4*>(qb + (size_t)tl * DH + d0);
    const float4 vk = *reinterpret_cast<const float4*>(kb + (size_t)tl * DH + d0);
    tq[tl][d0] = vq.x; tq[tl][d0 + 1] = vq.y; tq[tl][d0 + 2] = vq.z; tq[tl][d0 + 3] = vq.w;
    tk[tl][d0] = vk.x; tk[tl][d0 + 1] = vk.y; tk[tl][d0 + 2] = vk.z; tk[tl][d0 + 3] = vk.w;
  }
  __syncthreads();
  const int d = tid >> 2;
  const int s = tid & 3;
  float2* ob = zT + ((size_t)(bh * DH + d)) * LEN + t0;
#pragma unroll
  for (int r = 0; r < 8; ++r) {
    const int t = (s + r * 4) * 2;
    const float4 o = make_float4(tq[t][d], tk[t][d], tq[t + 1][d], tk[t + 1][d]);
    *reinterpret_cast<float4*>(&ob[t]) = o;
  }
}

// ---------------------------------------------------------------------------
// Pass A: one block per (bh, d-quad). For each of DPB d's: forward FFT of
// z = q_d + i*k_d as 16x16x16 (three in-register 16-pt DFTs + 2 LDS
// exchanges); position p holds Z[rev16(p)]. Cross-spectrum P[f] = Q conj(K)
// = Im(A*B)/2 + i(|A|^2-|B|^2)/4 (A=Z[f], B=Z[-f]) accumulated in an LDS
// buffer (zero register accumulators -> no spill), one partial slab written
// per block: 16 slabs/bh instead of 64.
// ---------------------------------------------------------------------------
template <bool TR>
__global__ __launch_bounds__(256, 2) void ac_fft_fwd(const float* __restrict__ q,
                                                     const float* __restrict__ k,
                                                     const float2* __restrict__ zin,
                                                     const float2* __restrict__ tw,
                                                     float2* __restrict__ part) {
  __shared__ float lre[16 * XSTR], lim[16 * XSTR];  // 34.8 KB
  __shared__ float2 acc[LEN];                       // 32 KB accumulator
  const int tid = threadIdx.x;
  const int hi = tid >> 4, lo = tid & 15;
  const int bh = blockIdx.x / NGRP;
  const int g = blockIdx.x % NGRP;

#pragma unroll
  for (int i = 0; i < 16; ++i) acc[tid + 256 * i] = make_float2(0.f, 0.f);

  for (int dd = 0; dd < DPB; ++dd) {
    const int d = g * DPB + dd;
    cf x[16];
    if (TR) {
      const float2* zb = zin + (size_t)(bh * DH + d) * LEN;
#pragma unroll
      for (int n1 = 0; n1 < 16; ++n1) {
        const float2 z = zb[tid + 256 * n1];
        x[n1].r = z.x; x[n1].i = z.y;
      }
    } else {
      const float* qb = q + (size_t)bh * LEN * DH + d;
      const float* kb = k + (size_t)bh * LEN * DH + d;
#pragma unroll
      for (int n1 = 0; n1 < 16; ++n1) {
        x[n1].r = qb[(size_t)(tid + 256 * n1) * DH];
        x[n1].i = kb[(size_t)(tid + 256 * n1) * DH];
      }
    }
    // stage 1: DFT over n1 (stride 256), twiddle W4096^{n2*k1}, n2 = tid
    dft16<-1>(x);
#pragma unroll
    for (int k1 = 1; k1 < 16; ++k1) {
      float wr, wi;
      twget<-1>(tw, tid * k1, wr, wi);
      x[k1] = cmul(x[k1], wr, wi);
    }
    __syncthreads();  // previous iteration's pairing reads complete
#pragma unroll
    for (int k1 = 0; k1 < 16; ++k1) {
      lre[k1 * XSTR + tid] = x[k1].r;
      lim[k1 * XSTR + tid] = x[k1].i;
    }
    __syncthreads();
    // stage 2 inputs: fixed (k1=hi, m2=lo), over m1
#pragma unroll
    for (int m1 = 0; m1 < 16; ++m1) {
      const int a = hi * XSTR + 16 * m1 + lo;
      x[m1].r = lre[a]; x[m1].i = lim[a];
    }
    dft16<-1>(x);
#pragma unroll
    for (int j1 = 1; j1 < 16; ++j1) {  // twiddle W256^{m2*j1} = W4096^{16*lo*j1}
      float wr, wi;
      twget<-1>(tw, 16 * lo * j1, wr, wi);
      x[j1] = cmul(x[j1], wr, wi);
    }
    __syncthreads();  // all stage-2 reads done
#pragma unroll
    for (int j1 = 0; j1 < 16; ++j1) {
      lre[hi * XSTR + 16 * j1 + lo] = x[j1].r;
      lim[hi * XSTR + 16 * j1 + lo] = x[j1].i;
    }
    __syncthreads();
    // stage 3 inputs: fixed (k1=hi, j1=lo), over m2 (contiguous 16)
#pragma unroll
    for (int m2 = 0; m2 < 16; ++m2) {
      const int a = hi * XSTR + 16 * lo + m2;
      x[m2].r = lre[a]; x[m2].i = lim[a];
    }
    dft16<-1>(x);
    __syncthreads();  // all stage-3 reads done
#pragma unroll
    for (int j2 = 0; j2 < 16; ++j2) {  // p = 256*hi + 16*lo + j2
      lre[hi * XSTR + 16 * lo + j2] = x[j2].r;
      lim[hi * XSTR + 16 * lo + j2] = x[j2].i;
    }
    __syncthreads();
    // cross-spectrum pairing (position p holds Z[rev16(p)]); accumulate in
    // LDS (each p owned by exactly one thread -> race-free rmw)
#pragma unroll
    for (int i = 0; i < 16; ++i) {
      const int p = tid + 256 * i;
      const int f = rev16_12(p);
      const int f2 = (LEN - f) & (LEN - 1);
      const int p2 = rev16_12(f2);
      const int a1 = i * XSTR + tid;
      const int a2 = (p2 >> 8) * XSTR + (p2 & 255);
      const float ar = lre[a1], ai = lim[a1];
      const float br = lre[a2], bi = lim[a2];
      float2 a = acc[p];
      a.x += 0.5f * (ar * bi + ai * br);
      a.y += 0.25f * ((ar * ar + ai * ai) - (br * br + bi * bi));
      acc[p] = a;
    }
  }
  // write the block's partial slab (coalesced float2)
  float2* op = part + (size_t)(bh * NGRP + g) * LEN;
#pragma unroll
  for (int i = 0; i < 16; ++i) {
    const int p = tid + 256 * i;
    op[p] = acc[p];
  }
}

// ---------------------------------------------------------------------------
// Pass R: sum 16 partial spectra -> spec[bh][p]. Grid NBH*16, coalesced.
// ---------------------------------------------------------------------------
__global__ __launch_bounds__(256) void ac_reduce(const float2* __restrict__ part,
                                                 float2* __restrict__ spec) {
  const int bh = blockIdx.x >> 4;
  const int p = ((blockIdx.x & 15) << 8) | threadIdx.x;
  float accr = 0.f, acci = 0.f;
#pragma unroll 4
  for (int g = 0; g < NGRP; ++g) {
    const float2 v = part[((size_t)(bh * NGRP + g) << LOG2LEN) + p];
    accr += v.x; acci += v.y;
  }
  spec[((size_t)bh << LOG2LEN) + p] = make_float2(accr, acci);
}

// ---------------------------------------------------------------------------
// Pass B+C: per (b,h): inverse FFT 16x16x16 (digit-reversed in -> natural
// out) fused with top-8 + softmax. Writes attn + delays only.
// ---------------------------------------------------------------------------
__global__ __launch_bounds__(256, 4) void ac_fft_inv(const float2* __restrict__ spec,
                                                     const float2* __restrict__ tw,
                                                     float* __restrict__ attn,
                                                     int* __restrict__ delays) {
  __shared__ float lre[16 * XSTR], lim[16 * XSTR];
  __shared__ float rv[256];
  __shared__ int ri[256];
  __shared__ float selv[KTOP];
  __shared__ int seli[KTOP];
  const int bh = blockIdx.x;
  const int tid = threadIdx.x;
  const int hi = tid >> 4, lo = tid & 15;
  const float2* sp = spec + ((size_t)bh << LOG2LEN);

  // input: position p = 16*tid + f2 holds P[rev16(p)]; thread = (f0=hi, f1=lo)
  cf x[16];
#pragma unroll
  for (int f2 = 0; f2 < 16; ++f2) {
    const float2 z = sp[16 * tid + f2];
    x[f2].r = z.x; x[f2].i = z.y;
  }
  // stage A: DFT over f2 -> A1[t0]; twiddle W4096^{16*f1*t0}
  dft16<1>(x);
#pragma unroll
  for (int t0 = 1; t0 < 16; ++t0) {
    float wr, wi;
    twget<1>(tw, 16 * lo * t0, wr, wi);
    x[t0] = cmul(x[t0], wr, wi);
  }
#pragma unroll
  for (int t0 = 0; t0 < 16; ++t0) {
    lre[hi * XSTR + 16 * t0 + lo] = x[t0].r;
    lim[hi * XSTR + 16 * t0 + lo] = x[t0].i;
  }
  __syncthreads();
  // stage B: thread (f0=hi, t0=lo), over f1 (contiguous)
#pragma unroll
  for (int f1 = 0; f1 < 16; ++f1) {
    const int a = hi * XSTR + 16 * lo + f1;
    x[f1].r = lre[a]; x[f1].i = lim[a];
  }
  dft16<1>(x);
#pragma unroll
  for (int t1 = 0; t1 < 16; ++t1) {  // twiddle W4096^{f0*(16*t1+t0)}
    float wr, wi;
    twget<1>(tw, hi * (16 * t1 + lo), wr, wi);
    x[t1] = cmul(x[t1], wr, wi);
  }
  __syncthreads();  // stage-B reads done
#pragma unroll
  for (int t1 = 0; t1 < 16; ++t1) {
    lre[hi * XSTR + 16 * t1 + lo] = x[t1].r;
    lim[hi * XSTR + 16 * t1 + lo] = x[t1].i;
  }
  __syncthreads();
  // stage C: thread (t1=hi, t0=lo), over f0 (stride XSTR)
#pragma unroll
  for (int f0 = 0; f0 < 16; ++f0) {
    const int a = f0 * XSTR + 16 * hi + lo;
    x[f0].r = lre[a]; x[f0].i = lim[a];
  }
  dft16<1>(x);
  __syncthreads();  // stage-C reads done; reuse lre as vals[4096]
  const float scale = 1.0f / ((float)LEN * (float)DH);
#pragma unroll
  for (int t2 = 0; t2 < 16; ++t2) lre[256 * t2 + tid] = x[t2].r * scale;  // t = 256*t2 + tid
  __syncthreads();

  // top-8 + softmax on vals = lre[0..4095]
  for (int kk = 0; kk < KTOP; ++kk) {
    float mv = -3.0e38f;
    int mi = 0;
    for (int t = tid; t < LEN; t += 256) {
      const float xv = lre[t];
      if (xv > mv) { mv = xv; mi = t; }
    }
    rv[tid] = mv; ri[tid] = mi;
    __syncthreads();
    for (int s = 128; s > 0; s >>= 1) {
      if (tid < s) {
        if (rv[tid + s] > rv[tid]) { rv[tid] = rv[tid + s]; ri[tid] = ri[tid + s]; }
      }
      __syncthreads();
    }
    if (tid == 0) {
      selv[kk] = rv[0];
      seli[kk] = ri[0];
      lre[ri[0]] = -3.0e38f;
    }
    __syncthreads();
  }
  if (tid == 0) {
    const float mx = selv[0];
    float ex[KTOP];
    float sum = 0.f;
    for (int j = 0; j < KTOP; ++j) { ex[j] = expf(selv[j] - mx); sum += ex[j]; }
    const float inv = 1.0f / sum;
    for (int j = 0; j < KTOP; ++j) {
      attn[bh * KTOP + j] = ex[j] * inv;
      delays[bh * KTOP + j] = seli[j];
    }
  }
}

// ---------------------------------------------------------------------------
// Pass D: out[bh,t,d] = sum_j attn_j * v[bh,(t-delay_j) mod L, d], float4.
// ---------------------------------------------------------------------------
__global__ __launch_bounds__(256) void ac_gather(const float* __restrict__ v,
                                                 const float* __restrict__ attn,
                                                 const int* __restrict__ delays,
                                                 float* __restrict__ out) {
  const int bx = blockIdx.x;
  const int xcd = bx & 7;
  const int i = bx >> 3;
  const int bh = (xcd << 2) | (i & 3);
  const int chunk = i >> 2;
  const int tid = threadIdx.x;
  float aw[KTOP];
  int dl[KTOP];
#pragma unroll
  for (int j = 0; j < KTOP; ++j) {
    aw[j] = attn[bh * KTOP + j];
    dl[j] = delays[bh * KTOP + j];
  }
  const int e = chunk * 1024 + tid * 4;
  const int t = e >> 6;
  const int d = e & 63;
  const float* vb = v + (size_t)bh * LEN * DH;
  float4 acc = make_float4(0.f, 0.f, 0.f, 0.f);
#pragma unroll
  for (int j = 0; j < KTOP; ++j) {
    int src = t - dl[j];
    if (src < 0) src += LEN;
    const float4 vv = *reinterpret_cast<const float4*>(vb + (size_t)src * DH + d);
    acc.x += aw[j] * vv.x;
    acc.y += aw[j] * vv.y;
    acc.z += aw[j] * vv.z;
    acc.w += aw[j] * vv.w;
  }
  *reinterpret_cast<float4*>(out + (size_t)bh * LEN * DH + e) = acc;
}

extern "C" void kernel_launch(void* const* d_in, const int* in_sizes, int n_in,
                              void* d_out, int out_size, void* d_ws, size_t ws_size,
                              hipStream_t stream) {
  const float* q = (const float*)d_in[0];
  const float* k = (const float*)d_in[1];
  const float* v = (const float*)d_in[2];
  float* out = (float*)d_out;

  // ws layout: tw | zT | part | spec | attn | delays  (~85 MB)
  const size_t need = (size_t)TW_N * 8 + ZT_ELEMS * 8 + PART_F2 * 8 +
                      (size_t)SPEC_F2 * 8 + (size_t)NBH * KTOP * 8;
  const bool tr = (ws_size >= need);

  float2* tw = (float2*)d_ws;
  float2* zT = tw + TW_N;
  float2* part = tr ? (zT + ZT_ELEMS) : zT;  // no-TR path: zT unused, reuse
  float2* spec = part + PART_F2;
  float* attn = (float*)(spec + SPEC_F2);
  int* delays = (int*)(attn + NBH * KTOP);

  if (tr) {
    ac_transpose<<<dim3(NBH * 64), dim3(256), 0, stream>>>(q, k, zT, tw);
    ac_fft_fwd<true><<<dim3(NBH * NGRP), dim3(256), 0, stream>>>(q, k, zT, tw, part);
  } else {
    ac_twinit<<<dim3(8), dim3(256), 0, stream>>>(tw);
    ac_fft_fwd<false><<<dim3(NBH * NGRP), dim3(256), 0, stream>>>(q, k, zT, tw, part);
  }
  ac_reduce<<<dim3(NBH * 16), dim3(256), 0, stream>>>(part, spec);
  ac_fft_inv<<<dim3(NBH), dim3(256), 0, stream>>>(spec, tw, attn, delays);
  ac_gather<<<dim3(NBH * 256), dim3(256), 0, stream>>>(v, attn, delays, out);
}